// Round 11
// baseline (1893.038 us; speedup 1.0000x reference)
//
#include <hip/hip_runtime.h>
#include <math.h>

// ---------------------------------------------------------------------------
// Round 11: OUTPUT IS FLOAT32 (reference output dtype complex64 -> "else
// float*" per harness doc; out_size = 262144 f32), PLANAR axis-0 layout:
//   out[oi] = Re(ksp), out[131072 + oi] = Im(ksp),
//   oi = ((t*8+ch)*4+d)*2048 + k       [np.stack([real, imag]) flattened]
// Inputs: dict order, f32 containers. Math (validated by two independent
// implementations agreeing bit-exactly):
//   ksp[t,ch,d,k] = sum_{y,x} image[t,d,y,x]*csm[t,ch,d,y,x]
//                           * exp(-i*(ky[t,k]*(y-64) + kx[t,k]*(x-64)))
//   ky = traj[t,0,k], kx = traj[t,1,k]
// ---------------------------------------------------------------------------

__global__ __launch_bounds__(128)
void nufft_f32planar(const float* __restrict__ imr, const float* __restrict__ imi,
                     const float* __restrict__ csr, const float* __restrict__ csi,
                     const float* __restrict__ traj, float* __restrict__ out)
{
    const int bx  = blockIdx.x;        // [0, 4096)
    const int t   = bx >> 11;
    const int k   = bx & 2047;
    const int tid = threadIdx.x;       // 0..127, lane = x column
    const int lane = tid & 63;
    const int wv   = tid >> 6;

    const float ky = traj[(t * 2 + 0) * 2048 + k];
    const float kx = traj[(t * 2 + 1) * 2048 + k];

    __shared__ float eyr[128], eyi[128];
    __shared__ float redr[2], redi[2];

    {
        const float cc = (float)(tid - 64);    // centered y
        float s, co;
        sincosf(-ky * cc, &s, &co);            // exp(-i*ky*(y-64))
        eyr[tid] = co; eyi[tid] = s;
    }
    __syncthreads();

    float exr_l, exi_l;
    {
        const float cc = (float)(tid - 64);    // centered x (lane = x)
        sincosf(-kx * cc, &exi_l, &exr_l);     // sin -> exi_l, cos -> exr_l
    }

    for (int n = 0; n < 32; ++n) {
        const int ch = n >> 2;
        const int d  = n & 3;
        const int ibase = (t * 4 + d) * 16384;
        const int cbase = ((t * 8 + ch) * 4 + d) * 16384;

        float aR = 0.f, aI = 0.f;
        for (int y = 0; y < 128; ++y) {
            const int off = y * 128 + tid;     // coalesced, lane = x
            const float ar = imr[ibase + off];
            const float ai = imi[ibase + off];
            const float br = csr[cbase + off];
            const float bi = csi[cbase + off];
            const float mr = ar * br - ai * bi;        // multi = image*csm
            const float mi = ar * bi + ai * br;
            const float vr = mr * exr_l - mi * exi_l;  // * Ex
            const float vi = mr * exi_l + mi * exr_l;
            aR += vr * eyr[y] - vi * eyi[y];           // * Ey, accumulate
            aI += vr * eyi[y] + vi * eyr[y];
        }

        for (int o = 32; o > 0; o >>= 1) {
            aR += __shfl_down(aR, o);
            aI += __shfl_down(aI, o);
        }
        if (lane == 0) { redr[wv] = aR; redi[wv] = aI; }
        __syncthreads();
        if (tid == 0) {
            const float sr = redr[0] + redr[1];
            const float si = redi[0] + redi[1];
            const int oi = ((t * 8 + ch) * 4 + d) * 2048 + k;
            out[oi]          = sr;     // REAL plane (f32)
            out[131072 + oi] = si;     // IMAG plane (f32)
        }
        __syncthreads();
    }
}

extern "C" void kernel_launch(void* const* d_in, const int* in_sizes, int n_in,
                              void* d_out, int out_size, void* d_ws, size_t ws_size,
                              hipStream_t stream) {
    const float* imr  = (const float*)d_in[0];   // image_real (dict order)
    const float* imi  = (const float*)d_in[1];   // image_imag
    const float* csr  = (const float*)d_in[2];   // csm_real
    const float* csi  = (const float*)d_in[3];   // csm_imag
    const float* traj = (const float*)d_in[4];   // traj

    nufft_f32planar<<<dim3(2 * 2048), dim3(128), 0, stream>>>(
        imr, imi, csr, csi, traj, (float*)d_out);
}

// Round 12
// 464.776 us; speedup vs baseline: 4.0730x; 4.0730x over previous
//
#include <hip/hip_runtime.h>
#include <math.h>

#define NT   2
#define NCH  8
#define ND   4
#define NH   128
#define NWI  128
#define NK   2048
#define KT   16      // k-values per block
#define NWAVES 8
#define NTHR (NWAVES * 64)
#define EPAD 130     // padded float2 row (1040 B: rows stay 16B-aligned, bank offset 4)

// multi workspace: planar  mR[(t*32+n)*16384 + y*128 + x], mI at +1048576 floats
#define MULTI_ELEMS 1048576
#define WS_NEEDED   (MULTI_ELEMS * 2 * sizeof(float))

// ---------------------------------------------------------------------------
// Kernel 1: multi = image * csm  (complex), planar f32 output into d_ws.
// 1024 blocks x 256 thr, float4 per thread: memory-bound, ~33 MB traffic.
// ---------------------------------------------------------------------------
__global__ __launch_bounds__(256)
void make_multi(const float* __restrict__ imr, const float* __restrict__ imi,
                const float* __restrict__ csr, const float* __restrict__ csi,
                float* __restrict__ mR, float* __restrict__ mI)
{
    const int gid = blockIdx.x * 256 + threadIdx.x;   // [0, 262144)
    const int p   = gid * 4;                          // flat px in [t][n][y][x]
    const int x   = p & 127;
    const int y   = (p >> 7) & 127;
    const int n   = (p >> 14) & 31;
    const int t   = p >> 19;
    const int d   = n & 3;
    const int ch  = n >> 2;

    const int io = ((t * 4 + d) * 128 + y) * 128 + x;
    const int co = (((t * 8 + ch) * 4 + d) * 128 + y) * 128 + x;

    const float4 ar = *(const float4*)(imr + io);
    const float4 ai = *(const float4*)(imi + io);
    const float4 br = *(const float4*)(csr + co);
    const float4 bi = *(const float4*)(csi + co);

    float4 mr, mi;
    mr.x = ar.x * br.x - ai.x * bi.x;  mi.x = ar.x * bi.x + ai.x * br.x;
    mr.y = ar.y * br.y - ai.y * bi.y;  mi.y = ar.y * bi.y + ai.y * br.y;
    mr.z = ar.z * br.z - ai.z * bi.z;  mi.z = ar.z * bi.z + ai.z * br.z;
    mr.w = ar.w * br.w - ai.w * bi.w;  mi.w = ar.w * bi.w + ai.w * br.w;

    *(float4*)(mR + p) = mr;
    *(float4*)(mI + p) = mi;
}

// ---------------------------------------------------------------------------
// Kernel 2: separable NUDFT. 256 blocks (t x 128 k-chunks), 512 threads.
// Waves split y (16 rows each); lane owns 4k x 2n outputs.
//   acc[k,n] = sum_y Ey[k,y] * (sum_x multi[n,y,x] * Ex[k,x])
// Output f32 planar: out[oi]=Re, out[131072+oi]=Im, oi=(t*32+n)*2048+k.
// ---------------------------------------------------------------------------
template<bool USEWS>
__global__ __launch_bounds__(NTHR, 2)
void nufft_sep(const float* __restrict__ imr, const float* __restrict__ imi,
               const float* __restrict__ csr, const float* __restrict__ csi,
               const float* __restrict__ traj,
               const float* __restrict__ mR, const float* __restrict__ mI,
               float* __restrict__ out)
{
    // eTab (33.3 KB) and red (32 KB) are union-overlapped; phases separated
    // by __syncthreads(). Total static LDS = 33.3 KB (< 64 KB limit).
    __shared__ __align__(16) unsigned char smraw[2 * KT * EPAD * sizeof(float2)];
    float2 (*eTab)[KT][EPAD] = reinterpret_cast<float2 (*)[KT][EPAD]>(smraw); // [2][KT][EPAD]
    float2 (*red)[KT * 32]   = reinterpret_cast<float2 (*)[KT * 32]>(smraw);  // [NWAVES][512]

    const int bid = blockIdx.x;
    // XCD swizzle: XCDs 0-3 -> t=0, 4-7 -> t=1; per-XCD multi working set 4.2MB
    const int xcd = bid & 7;
    const int t   = xcd >> 2;
    const int kc  = (xcd & 3) * 32 + (bid >> 3);   // bijective over [0,128)
    const int k0  = kc * KT;

    // ---- Phase 1: Ey/Ex tables: exp(-i * kv * (c-64)) ----
    for (int i = threadIdx.x; i < KT * 256; i += NTHR) {
        const int kk = i >> 8;
        const int r  = i & 255;
        const int ax = r >> 7;        // 0 -> y table, 1 -> x table
        const int c  = r & 127;
        const float kv = traj[(t * 2 + ax) * NK + k0 + kk];
        float s, co;
        sincosf(-kv * (float)(c - 64), &s, &co);
        eTab[ax][kk][c] = make_float2(co, s);
    }
    __syncthreads();

    const int wave = threadIdx.x >> 6;
    const int lane = threadIdx.x & 63;
    const int kg = lane >> 4;         // 0..3  -> k = kg*4 + rk
    const int ng = lane & 15;         // 0..15 -> n = 2*ng + rn
    const int n0 = ng * 2;
    const int ch = n0 >> 2;
    const int d0 = n0 & 3;
    const int d1 = d0 + 1;

    float accR[4][2], accI[4][2];
#pragma unroll
    for (int a = 0; a < 4; ++a)
#pragma unroll
        for (int b = 0; b < 2; ++b) { accR[a][b] = 0.f; accI[a][b] = 0.f; }

    const int yBeg = wave * (NH / NWAVES);
    const int yEnd = yBeg + (NH / NWAVES);

    for (int y = yBeg; y < yEnd; ++y) {
        float Rr[4][2], Ri[4][2];
#pragma unroll
        for (int a = 0; a < 4; ++a)
#pragma unroll
            for (int b = 0; b < 2; ++b) { Rr[a][b] = 0.f; Ri[a][b] = 0.f; }

        float2 eyv[4];
#pragma unroll
        for (int rk = 0; rk < 4; ++rk) eyv[rk] = eTab[0][kg * 4 + rk][y];

        const float* __restrict__ pm0r; const float* __restrict__ pm0i;
        const float* __restrict__ pm1r; const float* __restrict__ pm1i;
        const float* __restrict__ pc0r; const float* __restrict__ pc0i;
        const float* __restrict__ pc1r; const float* __restrict__ pc1i;
        const float* __restrict__ pi0r; const float* __restrict__ pi0i;
        const float* __restrict__ pi1r; const float* __restrict__ pi1i;
        if (USEWS) {
            pm0r = mR + ((t * 32 + n0    ) * 128 + y) * 128;
            pm0i = mI + ((t * 32 + n0    ) * 128 + y) * 128;
            pm1r = mR + ((t * 32 + n0 + 1) * 128 + y) * 128;
            pm1i = mI + ((t * 32 + n0 + 1) * 128 + y) * 128;
        } else {
            pc0r = csr + ((((size_t)t * NCH + ch) * ND + d0) * NH + y) * NWI;
            pc0i = csi + ((((size_t)t * NCH + ch) * ND + d0) * NH + y) * NWI;
            pc1r = csr + ((((size_t)t * NCH + ch) * ND + d1) * NH + y) * NWI;
            pc1i = csi + ((((size_t)t * NCH + ch) * ND + d1) * NH + y) * NWI;
            pi0r = imr + (((size_t)t * ND + d0) * NH + y) * NWI;
            pi0i = imi + (((size_t)t * ND + d0) * NH + y) * NWI;
            pi1r = imr + (((size_t)t * ND + d1) * NH + y) * NWI;
            pi1i = imi + (((size_t)t * ND + d1) * NH + y) * NWI;
        }

        for (int x = 0; x < NWI; x += 4) {
            float M0r[4], M0i[4], M1r[4], M1i[4];
            if (USEWS) {
                const float4 v0r = *(const float4*)(pm0r + x);
                const float4 v0i = *(const float4*)(pm0i + x);
                const float4 v1r = *(const float4*)(pm1r + x);
                const float4 v1i = *(const float4*)(pm1i + x);
                M0r[0]=v0r.x; M0r[1]=v0r.y; M0r[2]=v0r.z; M0r[3]=v0r.w;
                M0i[0]=v0i.x; M0i[1]=v0i.y; M0i[2]=v0i.z; M0i[3]=v0i.w;
                M1r[0]=v1r.x; M1r[1]=v1r.y; M1r[2]=v1r.z; M1r[3]=v1r.w;
                M1i[0]=v1i.x; M1i[1]=v1i.y; M1i[2]=v1i.z; M1i[3]=v1i.w;
            } else {
                const float4 b0r = *(const float4*)(pc0r + x);
                const float4 b0i = *(const float4*)(pc0i + x);
                const float4 b1r = *(const float4*)(pc1r + x);
                const float4 b1i = *(const float4*)(pc1i + x);
                const float4 a0r = *(const float4*)(pi0r + x);
                const float4 a0i = *(const float4*)(pi0i + x);
                const float4 a1r = *(const float4*)(pi1r + x);
                const float4 a1i = *(const float4*)(pi1i + x);
                const float A0r[4]={a0r.x,a0r.y,a0r.z,a0r.w}, A0i[4]={a0i.x,a0i.y,a0i.z,a0i.w};
                const float A1r[4]={a1r.x,a1r.y,a1r.z,a1r.w}, A1i[4]={a1i.x,a1i.y,a1i.z,a1i.w};
                const float B0r[4]={b0r.x,b0r.y,b0r.z,b0r.w}, B0i[4]={b0i.x,b0i.y,b0i.z,b0i.w};
                const float B1r[4]={b1r.x,b1r.y,b1r.z,b1r.w}, B1i[4]={b1i.x,b1i.y,b1i.z,b1i.w};
#pragma unroll
                for (int j = 0; j < 4; ++j) {
                    M0r[j] = A0r[j]*B0r[j] - A0i[j]*B0i[j];
                    M0i[j] = A0r[j]*B0i[j] + A0i[j]*B0r[j];
                    M1r[j] = A1r[j]*B1r[j] - A1i[j]*B1i[j];
                    M1i[j] = A1r[j]*B1i[j] + A1i[j]*B1r[j];
                }
            }

#pragma unroll
            for (int rk = 0; rk < 4; ++rk) {
                const float4* exk = (const float4*)eTab[1][kg * 4 + rk];
                const float4 e01 = exk[x >> 1];
                const float4 e23 = exk[(x >> 1) + 1];
                const float exr[4] = {e01.x, e01.z, e23.x, e23.z};
                const float exi[4] = {e01.y, e01.w, e23.y, e23.w};
#pragma unroll
                for (int j = 0; j < 4; ++j) {
                    Rr[rk][0] += M0r[j] * exr[j] - M0i[j] * exi[j];
                    Ri[rk][0] += M0r[j] * exi[j] + M0i[j] * exr[j];
                    Rr[rk][1] += M1r[j] * exr[j] - M1i[j] * exi[j];
                    Ri[rk][1] += M1r[j] * exi[j] + M1i[j] * exr[j];
                }
            }
        }

#pragma unroll
        for (int rk = 0; rk < 4; ++rk)
#pragma unroll
            for (int rn = 0; rn < 2; ++rn) {
                accR[rk][rn] += eyv[rk].x * Rr[rk][rn] - eyv[rk].y * Ri[rk][rn];
                accI[rk][rn] += eyv[rk].x * Ri[rk][rn] + eyv[rk].y * Rr[rk][rn];
            }
    }

    // ---- cross-wave reduction (red aliases eTab storage: barrier first) ----
    __syncthreads();
#pragma unroll
    for (int rk = 0; rk < 4; ++rk)
#pragma unroll
        for (int rn = 0; rn < 2; ++rn) {
            const int o = (kg * 4 + rk) * 32 + (n0 + rn);
            red[wave][o] = make_float2(accR[rk][rn], accI[rk][rn]);
        }
    __syncthreads();

    {
        const int o = threadIdx.x;    // NTHR == KT*32 == 512
        float sr = 0.f, si = 0.f;
#pragma unroll
        for (int w = 0; w < NWAVES; ++w) { sr += red[w][o].x; si += red[w][o].y; }
        const int kl = o >> 5;
        const int n  = o & 31;
        const int oi = (t * 32 + n) * NK + (k0 + kl);
        out[oi]          = sr;     // REAL plane (f32)
        out[131072 + oi] = si;     // IMAG plane (f32)
    }
}

extern "C" void kernel_launch(void* const* d_in, const int* in_sizes, int n_in,
                              void* d_out, int out_size, void* d_ws, size_t ws_size,
                              hipStream_t stream) {
    const float* imr  = (const float*)d_in[0];   // image_real (dict order)
    const float* imi  = (const float*)d_in[1];   // image_imag
    const float* csr  = (const float*)d_in[2];   // csm_real
    const float* csi  = (const float*)d_in[3];   // csm_imag
    const float* traj = (const float*)d_in[4];   // traj
    float* out = (float*)d_out;

    const int nblocks = NT * (NK / KT);   // 256

    if (ws_size >= WS_NEEDED) {
        float* mR = (float*)d_ws;
        float* mI = mR + MULTI_ELEMS;
        make_multi<<<dim3(MULTI_ELEMS / 4 / 256), dim3(256), 0, stream>>>(
            imr, imi, csr, csi, mR, mI);
        nufft_sep<true><<<dim3(nblocks), dim3(NTHR), 0, stream>>>(
            imr, imi, csr, csi, traj, mR, mI, out);
    } else {
        nufft_sep<false><<<dim3(nblocks), dim3(NTHR), 0, stream>>>(
            imr, imi, csr, csi, traj, nullptr, nullptr, out);
    }
}

// Round 13
// 72.560 us; speedup vs baseline: 26.0894x; 6.4054x over previous
//
#include <hip/hip_runtime.h>
#include <math.h>

typedef __attribute__((ext_vector_type(8))) short bf16x8;
typedef __attribute__((ext_vector_type(4))) float f32x4;

#define NK   2048
#define KT   16        // k per block tile
#define NTHR 512
#define PAD  17        // float2 row pad (bank-conflict-free-ish)

// ws layout: mRb bf16[1M] @0 (2MB), mIb @2MB (2MB), part f32[512*1024] @4MB (2MB)
#define MULTI_ELEMS (1 << 20)
#define PART_OFF    (4u << 20)
#define WS_NEEDED   (6u << 20)

__device__ __forceinline__ unsigned short f2bf(float f) {
    union { float f; unsigned u; } v; v.f = f;
    const unsigned r = (v.u + 0x7fffu + ((v.u >> 16) & 1u)) >> 16;  // RNE
    return (unsigned short)r;
}

// ---------------------------------------------------------------------------
// Kernel 1: multi = image*csm -> bf16 planes in ws. (indexing proven in R12)
// ---------------------------------------------------------------------------
__global__ __launch_bounds__(256)
void make_multi_bf16(const float* __restrict__ imr, const float* __restrict__ imi,
                     const float* __restrict__ csr, const float* __restrict__ csi,
                     unsigned short* __restrict__ mRb, unsigned short* __restrict__ mIb)
{
    const int gid = blockIdx.x * 256 + threadIdx.x;   // [0, 262144)
    const int p   = gid * 4;                          // flat [t][n][y][x]
    const int x   = p & 127;
    const int y   = (p >> 7) & 127;
    const int n   = (p >> 14) & 31;
    const int t   = p >> 19;
    const int d   = n & 3;
    const int ch  = n >> 2;
    const int io  = ((t * 4 + d) * 128 + y) * 128 + x;
    const int co  = (((t * 8 + ch) * 4 + d) * 128 + y) * 128 + x;

    const float4 ar = *(const float4*)(imr + io);
    const float4 ai = *(const float4*)(imi + io);
    const float4 br = *(const float4*)(csr + co);
    const float4 bi = *(const float4*)(csi + co);

    ushort4 sr, si;
    sr.x = f2bf(ar.x*br.x - ai.x*bi.x);  si.x = f2bf(ar.x*bi.x + ai.x*br.x);
    sr.y = f2bf(ar.y*br.y - ai.y*bi.y);  si.y = f2bf(ar.y*bi.y + ai.y*br.y);
    sr.z = f2bf(ar.z*br.z - ai.z*bi.z);  si.z = f2bf(ar.z*bi.z + ai.z*br.z);
    sr.w = f2bf(ar.w*br.w - ai.w*bi.w);  si.w = f2bf(ar.w*bi.w + ai.w*br.w);
    *(ushort4*)(mRb + p) = sr;
    *(ushort4*)(mIb + p) = si;
}

// ---------------------------------------------------------------------------
// Kernel 2: MFMA NUDFT. Grid 512 = 2t x 128 ktiles x 2 p-halves; 8 waves
// split the p-half (1024 p each, 32 steps of 32). Per step per lane:
// generate B-frag E[k0+(l&15)][p0+(l>>4)*8+j] from LDS Ey/Ex tables, load
// 4 A-frags (Mr,Mi x 2 n-tiles) from ws-bf16, 8 mfma into 4 accumulators.
// Cr = Mr*Er + Mi*(-Ei); Ci = Mr*Ei + Mi*Er.
// ---------------------------------------------------------------------------
__global__ __launch_bounds__(NTHR, 4)
void nufft_mfma(const float* __restrict__ traj,
                const unsigned short* __restrict__ mRb,
                const unsigned short* __restrict__ mIb,
                float* __restrict__ part)
{
    __shared__ float2 tab[2][128][PAD];   // [0]=Ey[y][kl], [1]=Ex[x][kl]  (~34 KB)
    __shared__ float  red[4][1024];       // cross-wave C reduction (16 KB)

    const int b   = blockIdx.x;
    // XCD swizzle: xcd = b&7; XCDs 0-3 -> t=0, 4-7 -> t=1 (multi[t]=4MB/XCD-L2)
    const int xcd = b & 7;
    const int t   = xcd >> 2;
    const int idx = (xcd & 3) * 64 + (b >> 3);   // bijective [0,256)
    const int kt  = idx >> 1;
    const int ph  = idx & 1;
    const int k0  = kt * KT;

    // ---- tables: exp(-i * kv * (c-64)), layout [c][kl] ----
    for (int i = threadIdx.x; i < 2 * 128 * KT; i += NTHR) {
        const int ax  = i >> 11;         // 0=y, 1=x
        const int rem = i & 2047;
        const int c   = rem >> 4;
        const int kl  = rem & 15;
        const float kv = traj[(t * 2 + ax) * NK + k0 + kl];
        float s, co;
        sincosf(-kv * (float)(c - 64), &s, &co);
        tab[ax][c][kl] = make_float2(co, s);
    }
    __syncthreads();

    const int wv = threadIdx.x >> 6;
    const int l  = threadIdx.x & 63;
    const int kl = l & 15;        // B: n-index (k_out); A: m-index (n_out)
    const int g  = l >> 4;        // k-group 0..3

    const unsigned short* pAr = mRb + (((size_t)t * 32) << 14);
    const unsigned short* pAi = mIb + (((size_t)t * 32) << 14);

    f32x4 accR0 = {0.f,0.f,0.f,0.f}, accI0 = {0.f,0.f,0.f,0.f};
    f32x4 accR1 = {0.f,0.f,0.f,0.f}, accI1 = {0.f,0.f,0.f,0.f};

    const int pbeg = ph * 8192 + wv * 1024;
    for (int s = 0; s < 32; ++s) {
        const int p0 = pbeg + s * 32;
        const int y  = p0 >> 7;                 // uniform within step
        const int x0 = (p0 & 127) + g * 8;

        // ---- generate E frags (8 complex per lane) ----
        const float2 ey = tab[0][y][kl];
        float er[8], eiN[8];
#pragma unroll
        for (int j = 0; j < 8; ++j) {
            const float2 ex = tab[1][x0 + j][kl];
            er[j]  = ey.x * ex.x - ey.y * ex.y;          //  Re(E)
            eiN[j] = -(ey.x * ex.y + ey.y * ex.x);       // -Im(E)
        }
        bf16x8 bEr, bEiN, bEi;
#pragma unroll
        for (int j = 0; j < 8; ++j) {
            bEr[j]  = (short)f2bf(er[j]);
            bEiN[j] = (short)f2bf(eiN[j]);
            bEi[j]  = (short)(bEiN[j] ^ (short)0x8000);  // +Im(E)
        }

        // ---- A frags: 8 contiguous bf16 at row (n), offset p ----
        const int pa = p0 + g * 8;
        const bf16x8 aR0 = *(const bf16x8*)(pAr + (((size_t)kl)      << 14) + pa);
        const bf16x8 aI0 = *(const bf16x8*)(pAi + (((size_t)kl)      << 14) + pa);
        const bf16x8 aR1 = *(const bf16x8*)(pAr + (((size_t)kl + 16) << 14) + pa);
        const bf16x8 aI1 = *(const bf16x8*)(pAi + (((size_t)kl + 16) << 14) + pa);

        accR0 = __builtin_amdgcn_mfma_f32_16x16x32_bf16(aR0, bEr,  accR0, 0, 0, 0);
        accR0 = __builtin_amdgcn_mfma_f32_16x16x32_bf16(aI0, bEiN, accR0, 0, 0, 0);
        accI0 = __builtin_amdgcn_mfma_f32_16x16x32_bf16(aR0, bEi,  accI0, 0, 0, 0);
        accI0 = __builtin_amdgcn_mfma_f32_16x16x32_bf16(aI0, bEr,  accI0, 0, 0, 0);
        accR1 = __builtin_amdgcn_mfma_f32_16x16x32_bf16(aR1, bEr,  accR1, 0, 0, 0);
        accR1 = __builtin_amdgcn_mfma_f32_16x16x32_bf16(aI1, bEiN, accR1, 0, 0, 0);
        accI1 = __builtin_amdgcn_mfma_f32_16x16x32_bf16(aR1, bEi,  accI1, 0, 0, 0);
        accI1 = __builtin_amdgcn_mfma_f32_16x16x32_bf16(aI1, bEr,  accI1, 0, 0, 0);
    }

    // ---- cross-wave reduction. D layout: row m=(l>>4)*4+r, col n=l&15 ----
    const int slot = wv & 3;
    if (wv < 4) {
#pragma unroll
        for (int r = 0; r < 4; ++r) {
            const int n0  = g * 4 + r;
            const int i00 = (n0 * 16 + kl) * 2;
            const int i10 = ((n0 + 16) * 16 + kl) * 2;
            red[slot][i00]     = accR0[r];
            red[slot][i00 + 1] = accI0[r];
            red[slot][i10]     = accR1[r];
            red[slot][i10 + 1] = accI1[r];
        }
    }
    __syncthreads();
    if (wv >= 4) {
#pragma unroll
        for (int r = 0; r < 4; ++r) {
            const int n0  = g * 4 + r;
            const int i00 = (n0 * 16 + kl) * 2;
            const int i10 = ((n0 + 16) * 16 + kl) * 2;
            red[slot][i00]     += accR0[r];
            red[slot][i00 + 1] += accI0[r];
            red[slot][i10]     += accR1[r];
            red[slot][i10 + 1] += accI1[r];
        }
    }
    __syncthreads();

    // ---- write 1024-f32 partial for (t, kt, ph) ----
    {
        const int bp = ((t * 128 + kt) * 2 + ph) * 1024;
#pragma unroll
        for (int f = threadIdx.x; f < 1024; f += NTHR)
            part[bp + f] = red[0][f] + red[1][f] + red[2][f] + red[3][f];
    }
}

// ---------------------------------------------------------------------------
// Kernel 3: sum the two p-half partials, write f32 planar output.
// ---------------------------------------------------------------------------
__global__ __launch_bounds__(256)
void reduce_out(const float* __restrict__ part, float* __restrict__ out)
{
    const int gidx = blockIdx.x * 256 + threadIdx.x;  // [0, 131072)
    const int t  = gidx >> 16;
    const int r1 = gidx & 65535;
    const int kt = r1 >> 9;
    const int r2 = r1 & 511;
    const int n  = r2 >> 4;
    const int kl = r2 & 15;

    const int bp = ((t * 128 + kt) * 2) * 1024;
    const int fr = (n * 16 + kl) * 2;
    const float re = part[bp + fr]     + part[bp + 1024 + fr];
    const float im = part[bp + fr + 1] + part[bp + 1024 + fr + 1];

    const int oi = (t * 32 + n) * 2048 + kt * KT + kl;
    out[oi]           = re;    // real plane
    out[131072 + oi]  = im;    // imag plane
}

extern "C" void kernel_launch(void* const* d_in, const int* in_sizes, int n_in,
                              void* d_out, int out_size, void* d_ws, size_t ws_size,
                              hipStream_t stream) {
    const float* imr  = (const float*)d_in[0];   // image_real (dict order)
    const float* imi  = (const float*)d_in[1];   // image_imag
    const float* csr  = (const float*)d_in[2];   // csm_real
    const float* csi  = (const float*)d_in[3];   // csm_imag
    const float* traj = (const float*)d_in[4];   // traj
    float* out = (float*)d_out;

    unsigned short* mRb = (unsigned short*)d_ws;
    unsigned short* mIb = mRb + MULTI_ELEMS;
    float* part = (float*)((char*)d_ws + PART_OFF);

    make_multi_bf16<<<dim3(1024), dim3(256), 0, stream>>>(imr, imi, csr, csi, mRb, mIb);
    nufft_mfma<<<dim3(512), dim3(NTHR), 0, stream>>>(traj, mRb, mIb, part);
    reduce_out<<<dim3(512), dim3(256), 0, stream>>>(part, out);
}